// Round 22
// baseline (147.595 us; speedup 1.0000x reference)
//
#include <hip/hip_runtime.h>
#include <hip/hip_bf16.h>
#include <cstdint>

// Problem constants: B=2, N=2048, C=1024, H=16, D=64
// Q is stored pre-scaled by D^-0.5 * log2(e) so softmax runs in exp2 domain.
// V is materialized TRANSPOSED in global memory (VtG[bh][d][n]) by the QKV GEMM.
// STATIC-MAX softmax: rms_norm bounds |S'| <= 8*log2e = 11.54 < 12 -> P = exp2(S'-12).
// R22: EARLY-BARRIER schedule. All LDS reads (QK K-frags + PV V-frags) happen BEFORE the
// per-iteration __syncthreads; softmax+PV run on registers in the unsynchronized region,
// and prefetch is issued 2 tiles deep right after the barrier (drain-free vmcnt at the
// next barrier). Same barrier count as R21; plain __syncthreads (race-free).
#define RMS_EPS 1.1920928955078125e-07f
#define SMAX 12.0f

typedef __bf16 bf16;
typedef __attribute__((ext_vector_type(8))) __bf16 bf16x8;
typedef __attribute__((ext_vector_type(4))) __bf16 bf16x4;
typedef __attribute__((ext_vector_type(4))) float f32x4;
typedef __attribute__((ext_vector_type(16))) float f32x16;
typedef unsigned int u32;
typedef __attribute__((ext_vector_type(2))) u32 u32x2;
typedef __attribute__((ext_vector_type(4))) u32 u32x4;

__device__ __forceinline__ void gload16(const bf16* g, bf16* l) {
  __builtin_amdgcn_global_load_lds(
      (__attribute__((address_space(1))) void*)(g),
      (__attribute__((address_space(3))) void*)(l), 16, 0, 0);
}

__device__ __forceinline__ float fexp2(float x) {
#if __has_builtin(__builtin_amdgcn_exp2f)
  return __builtin_amdgcn_exp2f(x);
#else
  return exp2f(x);
#endif
}

__device__ __forceinline__ u32 pack2(float a, float b) {
  unsigned short xa = __builtin_bit_cast(unsigned short, (bf16)a);
  unsigned short xb = __builtin_bit_cast(unsigned short, (bf16)b);
  return (u32)xa | ((u32)xb << 16);
}

// ---------------- fused f32 -> bf16 convert for all three inputs ----------------
__global__ __launch_bounds__(256) void cvt3_kernel(
    const float* __restrict__ x, const float* __restrict__ wq, const float* __restrict__ wp,
    bf16* __restrict__ xo, bf16* __restrict__ wqo, bf16* __restrict__ wpo) {
  int i = blockIdx.x * 256 + threadIdx.x;
  const float* s; bf16* d; int off;
  if (i < 524288) { s = x; d = xo; off = i; }
  else if (i < 917504) { s = wq; d = wqo; off = i - 524288; }
  else { s = wp; d = wpo; off = i - 917504; }
  const float4* s4 = (const float4*)s;
  float4 a = s4[off * 2], b = s4[off * 2 + 1];
  bf16x8 o;
  o[0] = (bf16)a.x; o[1] = (bf16)a.y; o[2] = (bf16)a.z; o[3] = (bf16)a.w;
  o[4] = (bf16)b.x; o[5] = (bf16)b.y; o[6] = (bf16)b.z; o[7] = (bf16)b.w;
  *(bf16x8*)(d + off * 8) = o;
}

// ---------------- GEMM C = A * B^T (R16, proven) ----------------
template <int MODE, int MINW>
__global__ __launch_bounds__(256, MINW) void gemm_bt(
    const bf16* __restrict__ A, const bf16* __restrict__ B,
    float* __restrict__ Cout, int Ncols,
    bf16* __restrict__ Qb, bf16* __restrict__ Kb, bf16* __restrict__ VtG,
    float* __restrict__ vninv) {
  union ShG {
    struct { bf16 As[128 * 64]; bf16 Bs[128 * 64]; } s;
    bf16 T[128 * 136];
  };
  __shared__ ShG shg;
  bf16* As = shg.s.As;
  bf16* Bs = shg.s.Bs;

  const int tid = threadIdx.x;
  const int wave = tid >> 6, lane = tid & 63;
  const int l15 = lane & 15, g = lane >> 4;
  const int nwg = gridDim.x * gridDim.y;
  const int wg0 = blockIdx.y * gridDim.x + blockIdx.x;
  const int wg = (wg0 & 7) * (nwg >> 3) + (wg0 >> 3);
  const int m0 = (wg / gridDim.x) * 128, n0 = (wg % gridDim.x) * 128;
  const int wr = wave >> 1, wc = wave & 1;

  f32x4 acc[4][4] = {};

  for (int k0 = 0; k0 < 1024; k0 += 64) {
    __syncthreads();
#pragma unroll
    for (int i = 0; i < 4; ++i) {
      const int gid = (i * 4 + wave) * 64 + lane;
      const int row = gid >> 3, gk = gid & 7;
      const int srcoff = k0 + ((gk ^ (row & 7)) << 3);
      gload16(A + (m0 + row) * 1024 + srcoff, As + (i * 4 + wave) * 512);
      gload16(B + (n0 + row) * 1024 + srcoff, Bs + (i * 4 + wave) * 512);
    }
    __syncthreads();
#pragma unroll
    for (int kc = 0; kc < 2; ++kc) {
      bf16x8 af[4], bfb[4];
#pragma unroll
      for (int mi = 0; mi < 4; ++mi) {
        const int row = wr * 64 + mi * 16 + l15;
        af[mi] = *(const bf16x8*)&As[row * 64 + (((kc * 4 + g) ^ (l15 & 7)) << 3)];
      }
#pragma unroll
      for (int ni = 0; ni < 4; ++ni) {
        const int row = wc * 64 + ni * 16 + l15;
        bfb[ni] = *(const bf16x8*)&Bs[row * 64 + (((kc * 4 + g) ^ (l15 & 7)) << 3)];
      }
#pragma unroll
      for (int mi = 0; mi < 4; ++mi)
#pragma unroll
        for (int ni = 0; ni < 4; ++ni)
          acc[mi][ni] = __builtin_amdgcn_mfma_f32_16x16x32_bf16(af[mi], bfb[ni], acc[mi][ni], 0, 0, 0);
    }
  }

  if (MODE == 0) {
#pragma unroll
    for (int mi = 0; mi < 4; ++mi) {
      const int mrow = m0 + wr * 64 + mi * 16 + g * 4;
#pragma unroll
      for (int r = 0; r < 4; ++r) {
        float* cp = Cout + (long)(mrow + r) * Ncols + n0 + wc * 64 + l15;
#pragma unroll
        for (int ni = 0; ni < 4; ++ni) cp[ni * 16] = acc[mi][ni][r];
      }
    }
  } else {
    const int blk_which = n0 >> 10;
    const int ncol = n0 + wc * 64;
    const int h = (ncol >> 6) & 15;

    if (blk_which == 2) {
#pragma unroll
      for (int mi = 0; mi < 4; ++mi) {
#pragma unroll
        for (int r = 0; r < 4; ++r) {
          float ss = 0.f;
#pragma unroll
          for (int ni = 0; ni < 4; ++ni) ss += acc[mi][ni][r] * acc[mi][ni][r];
          ss += __shfl_xor(ss, 1); ss += __shfl_xor(ss, 2);
          ss += __shfl_xor(ss, 4); ss += __shfl_xor(ss, 8);
          if (l15 == 0) {
            const int m = m0 + wr * 64 + mi * 16 + g * 4 + r;
            const int b = m >> 11, nseq = m & 2047;
            vninv[(b * 16 + h) * 2048 + nseq] = 1.0f / fmaxf(sqrtf(ss), 1e-12f);
          }
        }
      }
      __syncthreads();
#pragma unroll
      for (int mi = 0; mi < 4; ++mi)
#pragma unroll
        for (int ni = 0; ni < 4; ++ni) {
          bf16x4 v4;
#pragma unroll
          for (int r = 0; r < 4; ++r) v4[r] = (bf16)acc[mi][ni][r];
          *(bf16x4*)&shg.T[(wc * 64 + ni * 16 + l15) * 136 + wr * 64 + mi * 16 + g * 4] = v4;
        }
      __syncthreads();
      const int c = tid >> 1, half = tid & 1;
      const int gcol = n0 + c;
      const int hh = (gcol >> 6) & 15, d = gcol & 63;
      const int mb = m0 >> 11, nseq0 = m0 & 2047;
      bf16* dst = VtG + ((long)(mb * 16 + hh) * 64 + d) * 2048 + nseq0 + half * 64;
      const bf16* src = &shg.T[c * 136 + half * 64];
#pragma unroll
      for (int i = 0; i < 8; ++i)
        *(bf16x8*)(dst + i * 8) = *(const bf16x8*)(src + i * 8);
    } else {
      float scv[4][4];
#pragma unroll
      for (int mi = 0; mi < 4; ++mi) {
#pragma unroll
        for (int r = 0; r < 4; ++r) {
          float ss = 0.f;
#pragma unroll
          for (int ni = 0; ni < 4; ++ni) ss += acc[mi][ni][r] * acc[mi][ni][r];
          ss += __shfl_xor(ss, 1); ss += __shfl_xor(ss, 2);
          ss += __shfl_xor(ss, 4); ss += __shfl_xor(ss, 8);
          const float sc = rsqrtf(ss * (1.0f / 64) + RMS_EPS);
          scv[mi][r] = (blk_which == 0) ? sc * (0.125f * 1.44269504088896340736f) : sc;
        }
      }
      __syncthreads();
#pragma unroll
      for (int mi = 0; mi < 4; ++mi)
#pragma unroll
        for (int r = 0; r < 4; ++r) {
          const float sc = scv[mi][r];
#pragma unroll
          for (int ni = 0; ni < 4; ++ni)
            shg.T[(wr * 64 + mi * 16 + g * 4 + r) * 136 + wc * 64 + ni * 16 + l15] =
                (bf16)(acc[mi][ni][r] * sc);
        }
      __syncthreads();
      bf16* QK = (blk_which == 0) ? Qb : Kb;
      const int c8 = tid & 7, chh = (tid >> 3) & 1, r0 = tid >> 4;
      const int hh = ((n0 + chh * 64) >> 6) & 15;
#pragma unroll
      for (int p = 0; p < 8; ++p) {
        const int rr = r0 + p * 16;
        const int m = m0 + rr;
        const int bq = m >> 11, nseq = m & 2047;
        *(bf16x8*)(QK + ((long)(bq * 16 + hh) * 2048 + nseq) * 64 + c8 * 8) =
            *(const bf16x8*)&shg.T[rr * 136 + chh * 64 + c8 * 8];
      }
    }
  }
}

// ---------------- flash attention, 4 warps x 32x32 MFMA, KVBLK=128, early-barrier ------
// Iter t (reads buf[cur], tile t): QK -> V-frags->regs -> barrier -> prefetch tile t+2
// into buf[cur] -> softmax+PV (registers). Tile t+1 sits in buf[cur^1], staged 2 iters
// ago; its loads drained at the barrier (vmcnt(0) waits on 1.5-iteration-old loads = free).
__global__ __launch_bounds__(256, 2) void attn_kernel(
    const bf16* __restrict__ Qb, const bf16* __restrict__ Kb, const bf16* __restrict__ VtG,
    const float* __restrict__ vninv, bf16* __restrict__ Yb) {
  __shared__ bf16 Ks[2][128 * 64];  // [j][d] linear, swizzle key (j^(j>>3))&7
  __shared__ bf16 Vt[2][64 * 128];  // [d][j] linear, swizzle key (d^(d>>3))&7

  const int tid = threadIdx.x;
  const int wq = tid >> 6;
  const int lane = tid & 63;
  const int l31 = lane & 31, hi = lane >> 5;
  // XCD swizzle (512 blocks % 8 == 0 -> bijective)
  const int wg = (blockIdx.x & 7) * (gridDim.x >> 3) + (blockIdx.x >> 3);
  const int bh = wg >> 4, qb = wg & 15;
  const int b = bh >> 4, h = bh & 15;
  const long off = (long)bh * (2048 * 64);
  const bf16* Qp = Qb + off;
  const bf16* Kp = Kb + off;
  const bf16* VtP = VtG + (long)bh * 64 * 2048;
  const int qrow = qb * 128 + wq * 32 + l31;

  // Q B-frags in registers: row q=l31, k = kc*16 + hi*8 + i
  bf16x8 qf[4];
#pragma unroll
  for (int kc = 0; kc < 4; ++kc)
    qf[kc] = *(const bf16x8*)&Qp[qrow * 64 + kc * 16 + hi * 8];

  f32x16 o[2] = {};   // O^T[d][q]: q=l31, d = (r&3)+8*(r>>2)+4*hi+32*dt
  f32x16 lacc = {};   // per-slot P-sum accumulator; reduced once in epilogue
  f32x16 minit;       // loop-invariant -SMAX C-init for the first QK MFMA
#pragma unroll
  for (int r = 0; r < 16; ++r) minit[r] = -SMAX;

  // staging offsets (4 granules each for K and Vt per thread)
  int koff[4], voff[4];
#pragma unroll
  for (int i = 0; i < 4; ++i) {
    const int chunk = i * 4 + wq;
    const int j = chunk * 8 + (lane >> 3);
    koff[i] = j * 64 + (((lane & 7) ^ ((j ^ (j >> 3)) & 7)) << 3);
    const int d = chunk * 4 + (lane >> 4);
    voff[i] = d * 2048 + (((lane & 15) ^ ((d ^ (d >> 3)) & 7)) << 3);
  }

  // prologue: stage tiles 0 and 1 (pipeline depth 2)
#pragma unroll
  for (int i = 0; i < 4; ++i) {
    const int chunk = i * 4 + wq;
    gload16(Kp + koff[i], &Ks[0][chunk * 512]);
    gload16(VtP + voff[i], &Vt[0][chunk * 512]);
    gload16(Kp + 128 * 64 + koff[i], &Ks[1][chunk * 512]);
    gload16(VtP + 128 + voff[i], &Vt[1][chunk * 512]);
  }
  __syncthreads();

  int cur = 0;
  for (int it = 0; it < 16; ++it) {
    const bf16* ks = &Ks[cur][0];
    const bf16* vt = &Vt[cur][0];

    // ---- read phase (all LDS reads of buf[cur]) ----
    // S^T - 12 = K * Q^T + (-12): first MFMA consumes the loop-invariant minit.
    f32x16 sv[4];
#pragma unroll
    for (int jt = 0; jt < 4; ++jt) {
      const int j = jt * 32 + l31;
      const int key = (j ^ (j >> 3)) & 7;
      {
        bf16x8 kf = *(const bf16x8*)&ks[j * 64 + ((hi ^ key) << 3)];
        sv[jt] = __builtin_amdgcn_mfma_f32_32x32x16_bf16(kf, qf[0], minit, 0, 0, 0);
      }
#pragma unroll
      for (int kc = 1; kc < 4; ++kc) {
        bf16x8 kf = *(const bf16x8*)&ks[j * 64 + (((2 * kc + hi) ^ key) << 3)];
        sv[jt] = __builtin_amdgcn_mfma_f32_32x32x16_bf16(kf, qf[kc], sv[jt], 0, 0, 0);
      }
    }
    // V A-frags -> registers (pi-permuted: two b64 runs per frag; R21-proven layout)
    bf16x8 vf[2][8];
#pragma unroll
    for (int dt = 0; dt < 2; ++dt) {
      const int d = dt * 32 + l31;
      const int key = (d ^ (d >> 3)) & 7;
#pragma unroll
      for (int kc = 0; kc < 8; ++kc) {
        const u32x2 lo64 = *(const u32x2*)&vt[d * 128 + (((2 * kc) ^ key) << 3) + 4 * hi];
        const u32x2 hi64 = *(const u32x2*)&vt[d * 128 + (((2 * kc + 1) ^ key) << 3) + 4 * hi];
        u32x4 q;
        q[0] = lo64[0]; q[1] = lo64[1]; q[2] = hi64[0]; q[3] = hi64[1];
        vf[dt][kc] = __builtin_bit_cast(bf16x8, q);
      }
    }

    __syncthreads();  // all reads of buf[cur] done; tile it+1's writes visible

    // ---- prefetch tile it+2 into the just-freed buf[cur] ----
    if (it + 2 < 16) {
      const int nb = (it + 2) * 128;
#pragma unroll
      for (int i = 0; i < 4; ++i) {
        const int chunk = i * 4 + wq;
        gload16(Kp + nb * 64 + koff[i], &Ks[cur][chunk * 512]);
        gload16(VtP + nb + voff[i], &Vt[cur][chunk * 512]);
      }
    }

    // ---- compute phase (registers only; waves drift freely) ----
    // P = exp2(S' - 12)
#pragma unroll
    for (int jt = 0; jt < 4; ++jt)
#pragma unroll
      for (int r = 0; r < 16; ++r) sv[jt][r] = fexp2(sv[jt][r]);

#pragma unroll
    for (int r = 0; r < 16; ++r)
      lacc[r] += (sv[0][r] + sv[1][r]) + (sv[2][r] + sv[3][r]);

    // P -> B-frags with ZERO exchange (k-slot permutation pi, R21-proven)
    u32 w[4][8];
#pragma unroll
    for (int jt = 0; jt < 4; ++jt)
#pragma unroll
      for (int i = 0; i < 8; ++i) w[jt][i] = pack2(sv[jt][2 * i], sv[jt][2 * i + 1]);

    // O^T += V^T * P
#pragma unroll
    for (int dt = 0; dt < 2; ++dt)
#pragma unroll
      for (int kc = 0; kc < 8; ++kc) {
        const int c = kc & 1, jt = kc >> 1;
        u32x4 pv;
        pv[0] = w[jt][4 * c + 0];
        pv[1] = w[jt][4 * c + 1];
        pv[2] = w[jt][4 * c + 2];
        pv[3] = w[jt][4 * c + 3];
        const bf16x8 pa = __builtin_bit_cast(bf16x8, pv);
        o[dt] = __builtin_amdgcn_mfma_f32_32x32x16_bf16(vf[dt][kc], pa, o[dt], 0, 0, 0);
      }

    cur ^= 1;
  }

  // one-time row-sum reduction: lrun = sum over 16 slots + cross-half
  float sm[16];
#pragma unroll
  for (int r = 0; r < 16; ++r) sm[r] = lacc[r];
#pragma unroll
  for (int s2 = 8; s2 > 0; s2 >>= 1)
#pragma unroll
    for (int r = 0; r < s2; ++r) sm[r] += sm[r + s2];
  const float lrun = sm[0] + __shfl_xor(sm[0], 32);

  // epilogue: y = O/l ; xsa: y -= (y . Vn) Vn ; store (B,N,C) bf16
  const float linv = 1.f / lrun;
  const float vni = vninv[bh * 2048 + qrow];
  const float cvn = vni * vni;
  const bf16* vq = VtP + qrow;
  float yv[2][16], vvf[2][16];
  float t = 0.f;
#pragma unroll
  for (int dt = 0; dt < 2; ++dt)
#pragma unroll
    for (int rr = 0; rr < 4; ++rr) {
#pragma unroll
      for (int e = 0; e < 4; ++e) {
        const int r = rr * 4 + e;  // d = e + 8*rr + 4*hi + 32*dt
        const int d = e + 8 * rr + 4 * hi + 32 * dt;
        const float y = o[dt][r] * linv;
        const float vx = (float)vq[d * 2048];
        yv[dt][r] = y; vvf[dt][r] = vx;
        t += y * vx;
      }
    }
  t += __shfl_xor(t, 32);
  const float coef = t * cvn;
  bf16* yp = Yb + ((long)b * 2048 + qrow) * 1024 + h * 64;
#pragma unroll
  for (int dt = 0; dt < 2; ++dt)
#pragma unroll
    for (int rr = 0; rr < 4; ++rr) {
      bf16x4 y4;
#pragma unroll
      for (int e = 0; e < 4; ++e) {
        const int r = rr * 4 + e;
        y4[e] = (bf16)(yv[dt][r] - coef * vvf[dt][r]);
      }
      *(bf16x4*)&yp[dt * 32 + rr * 8 + hi * 4] = y4;
    }
}

// ---------------- launch ----------------
extern "C" void kernel_launch(void* const* d_in, const int* in_sizes, int n_in,
                              void* d_out, int out_size, void* d_ws, size_t ws_size,
                              hipStream_t stream) {
  (void)in_sizes; (void)n_in; (void)out_size; (void)ws_size;
  const float* x = (const float*)d_in[0];
  const float* w_qkv = (const float*)d_in[1];
  const float* w_proj = (const float*)d_in[2];
  float* out = (float*)d_out;
  char* ws = (char*)d_ws;

  bf16* xb     = (bf16*)(ws);              //  8,388,608  x as bf16
  bf16* wqkvb  = (bf16*)(ws + 8388608);    //  6,291,456
  bf16* wprojb = (bf16*)(ws + 14680064);   //  2,097,152
  bf16* Qb     = (bf16*)(ws + 16777216);   //  8,388,608  rms-normed * 0.125*log2e
  bf16* Kb     = (bf16*)(ws + 25165824);   //  8,388,608  rms-normed
  bf16* VtG    = (bf16*)(ws + 33554432);   //  8,388,608  (B,H,D,N) V transposed
  float* vninv = (float*)(ws + 41943040);  //    524,288  1/max(||v||,1e-12)
  bf16* Yb     = (bf16*)(ws + 42467328);   //  8,388,608  (B,N,C) post-xsa

  cvt3_kernel<<<4096, 256, 0, stream>>>(x, w_qkv, w_proj, xb, wqkvb, wprojb);

  gemm_bt<1, 3><<<dim3(24, 32), 256, 0, stream>>>(xb, wqkvb, nullptr, 3072,
                                                  Qb, Kb, VtG, vninv);
  attn_kernel<<<512, 256, 0, stream>>>(Qb, Kb, VtG, vninv, Yb);
  gemm_bt<0, 2><<<dim3(8, 32), 256, 0, stream>>>(Yb, wprojb, out, 1024,
                                                 nullptr, nullptr, nullptr, nullptr);
}

// Round 23
// 122.208 us; speedup vs baseline: 1.2077x; 1.2077x over previous
//
#include <hip/hip_runtime.h>
#include <hip/hip_bf16.h>
#include <cstdint>

// Problem constants: B=2, N=2048, C=1024, H=16, D=64
// Q is stored pre-scaled by D^-0.5 * log2(e) so softmax runs in exp2 domain.
// V is materialized TRANSPOSED in global memory (VtG[bh][d][n]) by the QKV GEMM.
// STATIC-MAX softmax: rms_norm bounds |S'| <= 8*log2e = 11.54 < 12 -> P = exp2(S'-12).
// R23 = R21 verbatim (session best, 122.3us): zero-shuffle PV via k-slot permutation pi;
// R22's V-frags-in-registers variant exceeded the VGPR cap (128) and spilled — reverted.
#define RMS_EPS 1.1920928955078125e-07f
#define SMAX 12.0f

typedef __bf16 bf16;
typedef __attribute__((ext_vector_type(8))) __bf16 bf16x8;
typedef __attribute__((ext_vector_type(4))) __bf16 bf16x4;
typedef __attribute__((ext_vector_type(4))) float f32x4;
typedef __attribute__((ext_vector_type(16))) float f32x16;
typedef unsigned int u32;
typedef __attribute__((ext_vector_type(2))) u32 u32x2;
typedef __attribute__((ext_vector_type(4))) u32 u32x4;

__device__ __forceinline__ void gload16(const bf16* g, bf16* l) {
  __builtin_amdgcn_global_load_lds(
      (__attribute__((address_space(1))) void*)(g),
      (__attribute__((address_space(3))) void*)(l), 16, 0, 0);
}

__device__ __forceinline__ float fexp2(float x) {
#if __has_builtin(__builtin_amdgcn_exp2f)
  return __builtin_amdgcn_exp2f(x);
#else
  return exp2f(x);
#endif
}

__device__ __forceinline__ u32 pack2(float a, float b) {
  unsigned short xa = __builtin_bit_cast(unsigned short, (bf16)a);
  unsigned short xb = __builtin_bit_cast(unsigned short, (bf16)b);
  return (u32)xa | ((u32)xb << 16);
}

// ---------------- fused f32 -> bf16 convert for all three inputs ----------------
__global__ __launch_bounds__(256) void cvt3_kernel(
    const float* __restrict__ x, const float* __restrict__ wq, const float* __restrict__ wp,
    bf16* __restrict__ xo, bf16* __restrict__ wqo, bf16* __restrict__ wpo) {
  int i = blockIdx.x * 256 + threadIdx.x;
  const float* s; bf16* d; int off;
  if (i < 524288) { s = x; d = xo; off = i; }
  else if (i < 917504) { s = wq; d = wqo; off = i - 524288; }
  else { s = wp; d = wpo; off = i - 917504; }
  const float4* s4 = (const float4*)s;
  float4 a = s4[off * 2], b = s4[off * 2 + 1];
  bf16x8 o;
  o[0] = (bf16)a.x; o[1] = (bf16)a.y; o[2] = (bf16)a.z; o[3] = (bf16)a.w;
  o[4] = (bf16)b.x; o[5] = (bf16)b.y; o[6] = (bf16)b.z; o[7] = (bf16)b.w;
  *(bf16x8*)(d + off * 8) = o;
}

// ---------------- GEMM C = A * B^T (R16, proven) ----------------
template <int MODE, int MINW>
__global__ __launch_bounds__(256, MINW) void gemm_bt(
    const bf16* __restrict__ A, const bf16* __restrict__ B,
    float* __restrict__ Cout, int Ncols,
    bf16* __restrict__ Qb, bf16* __restrict__ Kb, bf16* __restrict__ VtG,
    float* __restrict__ vninv) {
  union ShG {
    struct { bf16 As[128 * 64]; bf16 Bs[128 * 64]; } s;
    bf16 T[128 * 136];
  };
  __shared__ ShG shg;
  bf16* As = shg.s.As;
  bf16* Bs = shg.s.Bs;

  const int tid = threadIdx.x;
  const int wave = tid >> 6, lane = tid & 63;
  const int l15 = lane & 15, g = lane >> 4;
  const int nwg = gridDim.x * gridDim.y;
  const int wg0 = blockIdx.y * gridDim.x + blockIdx.x;
  const int wg = (wg0 & 7) * (nwg >> 3) + (wg0 >> 3);
  const int m0 = (wg / gridDim.x) * 128, n0 = (wg % gridDim.x) * 128;
  const int wr = wave >> 1, wc = wave & 1;

  f32x4 acc[4][4] = {};

  for (int k0 = 0; k0 < 1024; k0 += 64) {
    __syncthreads();
#pragma unroll
    for (int i = 0; i < 4; ++i) {
      const int gid = (i * 4 + wave) * 64 + lane;
      const int row = gid >> 3, gk = gid & 7;
      const int srcoff = k0 + ((gk ^ (row & 7)) << 3);
      gload16(A + (m0 + row) * 1024 + srcoff, As + (i * 4 + wave) * 512);
      gload16(B + (n0 + row) * 1024 + srcoff, Bs + (i * 4 + wave) * 512);
    }
    __syncthreads();
#pragma unroll
    for (int kc = 0; kc < 2; ++kc) {
      bf16x8 af[4], bfb[4];
#pragma unroll
      for (int mi = 0; mi < 4; ++mi) {
        const int row = wr * 64 + mi * 16 + l15;
        af[mi] = *(const bf16x8*)&As[row * 64 + (((kc * 4 + g) ^ (l15 & 7)) << 3)];
      }
#pragma unroll
      for (int ni = 0; ni < 4; ++ni) {
        const int row = wc * 64 + ni * 16 + l15;
        bfb[ni] = *(const bf16x8*)&Bs[row * 64 + (((kc * 4 + g) ^ (l15 & 7)) << 3)];
      }
#pragma unroll
      for (int mi = 0; mi < 4; ++mi)
#pragma unroll
        for (int ni = 0; ni < 4; ++ni)
          acc[mi][ni] = __builtin_amdgcn_mfma_f32_16x16x32_bf16(af[mi], bfb[ni], acc[mi][ni], 0, 0, 0);
    }
  }

  if (MODE == 0) {
#pragma unroll
    for (int mi = 0; mi < 4; ++mi) {
      const int mrow = m0 + wr * 64 + mi * 16 + g * 4;
#pragma unroll
      for (int r = 0; r < 4; ++r) {
        float* cp = Cout + (long)(mrow + r) * Ncols + n0 + wc * 64 + l15;
#pragma unroll
        for (int ni = 0; ni < 4; ++ni) cp[ni * 16] = acc[mi][ni][r];
      }
    }
  } else {
    const int blk_which = n0 >> 10;
    const int ncol = n0 + wc * 64;
    const int h = (ncol >> 6) & 15;

    if (blk_which == 2) {
#pragma unroll
      for (int mi = 0; mi < 4; ++mi) {
#pragma unroll
        for (int r = 0; r < 4; ++r) {
          float ss = 0.f;
#pragma unroll
          for (int ni = 0; ni < 4; ++ni) ss += acc[mi][ni][r] * acc[mi][ni][r];
          ss += __shfl_xor(ss, 1); ss += __shfl_xor(ss, 2);
          ss += __shfl_xor(ss, 4); ss += __shfl_xor(ss, 8);
          if (l15 == 0) {
            const int m = m0 + wr * 64 + mi * 16 + g * 4 + r;
            const int b = m >> 11, nseq = m & 2047;
            vninv[(b * 16 + h) * 2048 + nseq] = 1.0f / fmaxf(sqrtf(ss), 1e-12f);
          }
        }
      }
      __syncthreads();
#pragma unroll
      for (int mi = 0; mi < 4; ++mi)
#pragma unroll
        for (int ni = 0; ni < 4; ++ni) {
          bf16x4 v4;
#pragma unroll
          for (int r = 0; r < 4; ++r) v4[r] = (bf16)acc[mi][ni][r];
          *(bf16x4*)&shg.T[(wc * 64 + ni * 16 + l15) * 136 + wr * 64 + mi * 16 + g * 4] = v4;
        }
      __syncthreads();
      const int c = tid >> 1, half = tid & 1;
      const int gcol = n0 + c;
      const int hh = (gcol >> 6) & 15, d = gcol & 63;
      const int mb = m0 >> 11, nseq0 = m0 & 2047;
      bf16* dst = VtG + ((long)(mb * 16 + hh) * 64 + d) * 2048 + nseq0 + half * 64;
      const bf16* src = &shg.T[c * 136 + half * 64];
#pragma unroll
      for (int i = 0; i < 8; ++i)
        *(bf16x8*)(dst + i * 8) = *(const bf16x8*)(src + i * 8);
    } else {
      float scv[4][4];
#pragma unroll
      for (int mi = 0; mi < 4; ++mi) {
#pragma unroll
        for (int r = 0; r < 4; ++r) {
          float ss = 0.f;
#pragma unroll
          for (int ni = 0; ni < 4; ++ni) ss += acc[mi][ni][r] * acc[mi][ni][r];
          ss += __shfl_xor(ss, 1); ss += __shfl_xor(ss, 2);
          ss += __shfl_xor(ss, 4); ss += __shfl_xor(ss, 8);
          const float sc = rsqrtf(ss * (1.0f / 64) + RMS_EPS);
          scv[mi][r] = (blk_which == 0) ? sc * (0.125f * 1.44269504088896340736f) : sc;
        }
      }
      __syncthreads();
#pragma unroll
      for (int mi = 0; mi < 4; ++mi)
#pragma unroll
        for (int r = 0; r < 4; ++r) {
          const float sc = scv[mi][r];
#pragma unroll
          for (int ni = 0; ni < 4; ++ni)
            shg.T[(wr * 64 + mi * 16 + g * 4 + r) * 136 + wc * 64 + ni * 16 + l15] =
                (bf16)(acc[mi][ni][r] * sc);
        }
      __syncthreads();
      bf16* QK = (blk_which == 0) ? Qb : Kb;
      const int c8 = tid & 7, chh = (tid >> 3) & 1, r0 = tid >> 4;
      const int hh = ((n0 + chh * 64) >> 6) & 15;
#pragma unroll
      for (int p = 0; p < 8; ++p) {
        const int rr = r0 + p * 16;
        const int m = m0 + rr;
        const int bq = m >> 11, nseq = m & 2047;
        *(bf16x8*)(QK + ((long)(bq * 16 + hh) * 2048 + nseq) * 64 + c8 * 8) =
            *(const bf16x8*)&shg.T[rr * 136 + chh * 64 + c8 * 8];
      }
    }
  }
}

// ---------------- flash attention, 4 warps x 32x32 MFMA, swapped operands, KVBLK=128 ----
// R21 config (512 blocks x 256 threads, 2 blocks/CU), ZERO-SHUFFLE PV (k-slot perm pi).
__global__ __launch_bounds__(256, 2) void attn_kernel(
    const bf16* __restrict__ Qb, const bf16* __restrict__ Kb, const bf16* __restrict__ VtG,
    const float* __restrict__ vninv, bf16* __restrict__ Yb) {
  __shared__ bf16 Ks[2][128 * 64];  // [j][d] linear, swizzle key (j^(j>>3))&7
  __shared__ bf16 Vt[2][64 * 128];  // [d][j] linear, swizzle key (d^(d>>3))&7

  const int tid = threadIdx.x;
  const int wq = tid >> 6;
  const int lane = tid & 63;
  const int l31 = lane & 31, hi = lane >> 5;
  // XCD swizzle (512 blocks % 8 == 0 -> bijective)
  const int wg = (blockIdx.x & 7) * (gridDim.x >> 3) + (blockIdx.x >> 3);
  const int bh = wg >> 4, qb = wg & 15;
  const int b = bh >> 4, h = bh & 15;
  const long off = (long)bh * (2048 * 64);
  const bf16* Qp = Qb + off;
  const bf16* Kp = Kb + off;
  const bf16* VtP = VtG + (long)bh * 64 * 2048;
  const int qrow = qb * 128 + wq * 32 + l31;

  // Q B-frags in registers: row q=l31, k = kc*16 + hi*8 + i
  bf16x8 qf[4];
#pragma unroll
  for (int kc = 0; kc < 4; ++kc)
    qf[kc] = *(const bf16x8*)&Qp[qrow * 64 + kc * 16 + hi * 8];

  f32x16 o[2] = {};   // O^T[d][q]: q=l31, d = (r&3)+8*(r>>2)+4*hi+32*dt
  f32x16 lacc = {};   // per-slot P-sum accumulator; reduced once in epilogue
  f32x16 minit;       // loop-invariant -SMAX C-init for the first QK MFMA
#pragma unroll
  for (int r = 0; r < 16; ++r) minit[r] = -SMAX;

  // staging offsets (4 granules each for K and Vt per thread)
  int koff[4], voff[4];
#pragma unroll
  for (int i = 0; i < 4; ++i) {
    const int chunk = i * 4 + wq;
    const int j = chunk * 8 + (lane >> 3);
    koff[i] = j * 64 + (((lane & 7) ^ ((j ^ (j >> 3)) & 7)) << 3);
    const int d = chunk * 4 + (lane >> 4);
    voff[i] = d * 2048 + (((lane & 15) ^ ((d ^ (d >> 3)) & 7)) << 3);
  }

  // prologue: stage kv tile 0
#pragma unroll
  for (int i = 0; i < 4; ++i) {
    const int chunk = i * 4 + wq;
    gload16(Kp + koff[i], &Ks[0][chunk * 512]);
    gload16(VtP + voff[i], &Vt[0][chunk * 512]);
  }
  __syncthreads();

  int cur = 0;
  for (int it = 0; it < 16; ++it) {
    const int kv0 = it * 128;
    if (it < 15) {  // async prefetch next fat tile (T14)
#pragma unroll
      for (int i = 0; i < 4; ++i) {
        const int chunk = i * 4 + wq;
        gload16(Kp + (kv0 + 128) * 64 + koff[i], &Ks[cur ^ 1][chunk * 512]);
        gload16(VtP + (kv0 + 128) + voff[i], &Vt[cur ^ 1][chunk * 512]);
      }
    }
    const bf16* ks = &Ks[cur][0];
    const bf16* vt = &Vt[cur][0];

    // S^T - 12 = K * Q^T + (-12): first MFMA consumes the loop-invariant minit.
    f32x16 sv[4];
#pragma unroll
    for (int jt = 0; jt < 4; ++jt) {
      const int j = jt * 32 + l31;
      const int key = (j ^ (j >> 3)) & 7;
      {
        bf16x8 kf = *(const bf16x8*)&ks[j * 64 + ((hi ^ key) << 3)];
        sv[jt] = __builtin_amdgcn_mfma_f32_32x32x16_bf16(kf, qf[0], minit, 0, 0, 0);
      }
#pragma unroll
      for (int kc = 1; kc < 4; ++kc) {
        bf16x8 kf = *(const bf16x8*)&ks[j * 64 + (((2 * kc + hi) ^ key) << 3)];
        sv[jt] = __builtin_amdgcn_mfma_f32_32x32x16_bf16(kf, qf[kc], sv[jt], 0, 0, 0);
      }
    }

    // P = exp2(S' - 12); no max tracking needed (|S'| <= 11.54 by rms-norm bound)
#pragma unroll
    for (int jt = 0; jt < 4; ++jt)
#pragma unroll
      for (int r = 0; r < 16; ++r) sv[jt][r] = fexp2(sv[jt][r]);

    // row-sum accumulate only (reduction tree deferred to epilogue)
#pragma unroll
    for (int r = 0; r < 16; ++r)
      lacc[r] += (sv[0][r] + sv[1][r]) + (sv[2][r] + sv[3][r]);

    // ---- P -> B-frags with ZERO exchange (k-slot permutation pi) ----
    u32 w[4][8];
#pragma unroll
    for (int jt = 0; jt < 4; ++jt)
#pragma unroll
      for (int i = 0; i < 8; ++i) w[jt][i] = pack2(sv[jt][2 * i], sv[jt][2 * i + 1]);
    bf16x8 pafr[8];
#pragma unroll
    for (int kc = 0; kc < 8; ++kc) {
      const int c = kc & 1, jt = kc >> 1;
      u32x4 pv;
      pv[0] = w[jt][4 * c + 0];
      pv[1] = w[jt][4 * c + 1];
      pv[2] = w[jt][4 * c + 2];
      pv[3] = w[jt][4 * c + 3];
      pafr[kc] = __builtin_bit_cast(bf16x8, pv);
    }

    // O^T += V^T * P with pi-permuted A-frag: slot k of lane (d,hi) holds
    // V^T[d][16kc + pi(hi*8+i)] -> two b64 runs at j = 16kc+4hi and 16kc+8+4hi.
#pragma unroll
    for (int dt = 0; dt < 2; ++dt) {
      const int d = dt * 32 + l31;
      const int key = (d ^ (d >> 3)) & 7;
#pragma unroll
      for (int kc = 0; kc < 8; ++kc) {
        const u32x2 lo64 = *(const u32x2*)&vt[d * 128 + (((2 * kc) ^ key) << 3) + 4 * hi];
        const u32x2 hi64 = *(const u32x2*)&vt[d * 128 + (((2 * kc + 1) ^ key) << 3) + 4 * hi];
        u32x4 q;
        q[0] = lo64[0]; q[1] = lo64[1]; q[2] = hi64[0]; q[3] = hi64[1];
        const bf16x8 vf = __builtin_bit_cast(bf16x8, q);
        o[dt] = __builtin_amdgcn_mfma_f32_32x32x16_bf16(vf, pafr[kc], o[dt], 0, 0, 0);
      }
    }

    __syncthreads();
    cur ^= 1;
  }

  // one-time row-sum reduction: lrun = sum over 16 slots + cross-half
  float sm[16];
#pragma unroll
  for (int r = 0; r < 16; ++r) sm[r] = lacc[r];
#pragma unroll
  for (int s2 = 8; s2 > 0; s2 >>= 1)
#pragma unroll
    for (int r = 0; r < s2; ++r) sm[r] += sm[r + s2];
  const float lrun = sm[0] + __shfl_xor(sm[0], 32);

  // epilogue: y = O/l ; xsa: y -= (y . Vn) Vn ; store (B,N,C) bf16
  const float linv = 1.f / lrun;
  const float vni = vninv[bh * 2048 + qrow];
  const float cvn = vni * vni;
  const bf16* vq = VtP + qrow;
  float yv[2][16], vvf[2][16];
  float t = 0.f;
#pragma unroll
  for (int dt = 0; dt < 2; ++dt)
#pragma unroll
    for (int rr = 0; rr < 4; ++rr) {
#pragma unroll
      for (int e = 0; e < 4; ++e) {
        const int r = rr * 4 + e;  // d = e + 8*rr + 4*hi + 32*dt
        const int d = e + 8 * rr + 4 * hi + 32 * dt;
        const float y = o[dt][r] * linv;
        const float vx = (float)vq[d * 2048];
        yv[dt][r] = y; vvf[dt][r] = vx;
        t += y * vx;
      }
    }
  t += __shfl_xor(t, 32);
  const float coef = t * cvn;
  bf16* yp = Yb + ((long)b * 2048 + qrow) * 1024 + h * 64;
#pragma unroll
  for (int dt = 0; dt < 2; ++dt)
#pragma unroll
    for (int rr = 0; rr < 4; ++rr) {
      bf16x4 y4;
#pragma unroll
      for (int e = 0; e < 4; ++e) {
        const int r = rr * 4 + e;
        y4[e] = (bf16)(yv[dt][r] - coef * vvf[dt][r]);
      }
      *(bf16x4*)&yp[dt * 32 + rr * 8 + hi * 4] = y4;
    }
}

// ---------------- launch ----------------
extern "C" void kernel_launch(void* const* d_in, const int* in_sizes, int n_in,
                              void* d_out, int out_size, void* d_ws, size_t ws_size,
                              hipStream_t stream) {
  (void)in_sizes; (void)n_in; (void)out_size; (void)ws_size;
  const float* x = (const float*)d_in[0];
  const float* w_qkv = (const float*)d_in[1];
  const float* w_proj = (const float*)d_in[2];
  float* out = (float*)d_out;
  char* ws = (char*)d_ws;

  bf16* xb     = (bf16*)(ws);              //  8,388,608  x as bf16
  bf16* wqkvb  = (bf16*)(ws + 8388608);    //  6,291,456
  bf16* wprojb = (bf16*)(ws + 14680064);   //  2,097,152
  bf16* Qb     = (bf16*)(ws + 16777216);   //  8,388,608  rms-normed * 0.125*log2e
  bf16* Kb     = (bf16*)(ws + 25165824);   //  8,388,608  rms-normed
  bf16* VtG    = (bf16*)(ws + 33554432);   //  8,388,608  (B,H,D,N) V transposed
  float* vninv = (float*)(ws + 41943040);  //    524,288  1/max(||v||,1e-12)
  bf16* Yb     = (bf16*)(ws + 42467328);   //  8,388,608  (B,N,C) post-xsa

  cvt3_kernel<<<4096, 256, 0, stream>>>(x, w_qkv, w_proj, xb, wqkvb, wprojb);

  gemm_bt<1, 3><<<dim3(24, 32), 256, 0, stream>>>(xb, wqkvb, nullptr, 3072,
                                                  Qb, Kb, VtG, vninv);
  attn_kernel<<<512, 256, 0, stream>>>(Qb, Kb, VtG, vninv, Yb);
  gemm_bt<0, 2><<<dim3(8, 32), 256, 0, stream>>>(Yb, wprojb, out, 1024,
                                                 nullptr, nullptr, nullptr, nullptr);
}